// Round 12
// baseline (169.783 us; speedup 1.0000x reference)
//
#include <hip/hip_runtime.h>
#include <hip/hip_bf16.h>

typedef __bf16 bf16_t;
typedef __bf16 bf16x8 __attribute__((ext_vector_type(8)));
typedef __bf16 bf16x4 __attribute__((ext_vector_type(4)));
typedef float  f32x4  __attribute__((ext_vector_type(4)));

#define MFMA16(a, b, c) __builtin_amdgcn_mfma_f32_16x16x32_bf16((a), (b), (c), 0, 0, 0)

constexpr int E  = 1024;
constexpr int S  = 2048;
constexpr int H  = 16;
constexpr int M  = 4096;  // B*S

// ---------------------------------------------------------------------------
// async global->LDS 16B (wave-uniform LDS base + lane*16)
// ---------------------------------------------------------------------------
__device__ __forceinline__ void glds16(const bf16_t* src, bf16_t* dst) {
  __builtin_amdgcn_global_load_lds(
      (const __attribute__((address_space(1))) void*)src,
      (__attribute__((address_space(3))) void*)dst, 16, 0, 0);
}

// Stage a [ROWS x 64] bf16 tile (global row stride gld) into LDS, XOR-swizzled.
// NT = participating threads (pass a local tid in [0,NT)).
template <int ROWS, int NT>
__device__ __forceinline__ void stage_tile(const bf16_t* g, int gld,
                                           bf16_t* lds, int tid) {
  const int w = tid >> 6, l = tid & 63;
#pragma unroll
  for (int i = 0; i < ROWS * 8 / NT; ++i) {
    const int c = i * NT + w * 64 + l;
    const int row = c >> 3;
    const int gch = (c & 7) ^ (row & 7);
    glds16(g + (size_t)row * gld + gch * 8, lds + (size_t)(i * NT + w * 64) * 8);
  }
}

// Stage a [64 x 128] bf16 tile (row stride gld) into LDS, XOR-swizzled in
// 16B chunks within each row. NT=256: 4 glds/thread.
__device__ __forceinline__ void stage_v128(const bf16_t* g, int gld,
                                           bf16_t* lds, int tid) {
#pragma unroll
  for (int i = 0; i < 4; ++i) {
    const int c = i * 256 + tid;          // [0,1024)
    const int row = c >> 4, col16 = c & 15;
    const int gch = col16 ^ (row & 7);
    glds16(g + (size_t)row * gld + gch * 8, lds + (size_t)c * 8);
  }
}

// Stage interleaved A-chunk c of a 256-row tile (qkv kernel helper).
__device__ __forceinline__ void stage_A_chunk(const bf16_t* g, int c,
                                              bf16_t* lds, int tid) {
  const int w = tid >> 6, l = tid & 63;
#pragma unroll
  for (int i = 0; i < 2; ++i) {
    const int gc = i * 512 + w * 64 + l;      // [0,1024)
    const int row_l = gc >> 3;                // [0,128)
    const int col8 = gc & 7;
    const int h = row_l >> 6, rr = row_l & 63;
    const int row = h * 128 + c * 64 + rr;    // LDS == global row
    const int gch = col8 ^ (row & 7);
    glds16(g + (size_t)row * E + gch * 8, lds + ((size_t)row * 8 + col8) * 8);
  }
}

// Read an 8-elem k-chunk (kc in [0,8)) of row `row` from a swizzled [R x 64] tile.
__device__ __forceinline__ bf16x8 read_frag(const bf16_t* lds, int row, int kc) {
  return *(const bf16x8*)(lds + (size_t)((row << 3) + (kc ^ (row & 7))) * 8);
}

// Read an 8-elem chunk (kc in [0,16)) of row `row` from a swizzled [64 x 128] tile.
__device__ __forceinline__ bf16x8 read_v128(const bf16_t* lds, int row, int kc) {
  return *(const bf16x8*)(lds + (size_t)((row << 4) + (kc ^ (row & 7))) * 8);
}

// pack 2 f32 -> 1 u32 of 2 bf16 (lo=a, hi=b), one full-rate inst (T12)
__device__ __forceinline__ unsigned cvtpk(float a, float b) {
  unsigned r;
  asm("v_cvt_pk_bf16_f32 %0, %1, %2" : "=v"(r) : "v"(a), "v"(b));
  return r;
}

// ---------------------------------------------------------------------------
// fused fp32->bf16 conversion, v2: 32B read / 16B write per thread.
// ---------------------------------------------------------------------------
__global__ void cvt_all_kernel(const float* __restrict__ x,
                               const float* __restrict__ w0, const float* __restrict__ w1,
                               const float* __restrict__ w2, const float* __restrict__ w3,
                               bf16_t* __restrict__ xb,
                               bf16_t* __restrict__ o0, bf16_t* __restrict__ o1,
                               bf16_t* __restrict__ o2, bf16_t* __restrict__ o3) {
  const int bid = blockIdx.x;
  const float* s;
  bf16_t* d;
  int idx;
  if (bid < 2048) {
    s = x; d = xb; idx = bid * 256 + threadIdx.x;
  } else {
    const int seg = (bid - 2048) >> 9;
    s = seg == 0 ? w0 : seg == 1 ? w1 : seg == 2 ? w2 : w3;
    d = seg == 0 ? o0 : seg == 1 ? o1 : seg == 2 ? o2 : o3;
    idx = ((bid - 2048) & 511) * 256 + threadIdx.x;
  }
  float4 v0 = ((const float4*)s)[idx * 2];
  float4 v1 = ((const float4*)s)[idx * 2 + 1];
  bf16x8 o;
  o[0] = (bf16_t)v0.x; o[1] = (bf16_t)v0.y; o[2] = (bf16_t)v0.z; o[3] = (bf16_t)v0.w;
  o[4] = (bf16_t)v1.x; o[5] = (bf16_t)v1.y; o[6] = (bf16_t)v1.z; o[7] = (bf16_t)v1.w;
  ((bf16x8*)d)[idx] = o;
}

// ---------------------------------------------------------------------------
// fused QKV projection, v5 (kept): counted-vmcnt 4-phase schedule at 256x192,
// grid 16x16 = 256 blocks (all CUs). W fused [3072][1024]; Q/K row-major;
// V -> sigma-permuted VT. Q PRE-SCALED by log2(e)/8.
// ---------------------------------------------------------------------------
__global__ __launch_bounds__(512, 1) void qkv8_kernel(
    const bf16_t* __restrict__ xb, const bf16_t* __restrict__ W3,
    const float* __restrict__ bq, const float* __restrict__ bk,
    const float* __restrict__ bv, bf16_t* __restrict__ QKb,
    bf16_t* __restrict__ VT) {
  __shared__ __align__(16) bf16_t As[2][256 * 64];  // 64 KB
  __shared__ __align__(16) bf16_t Bs[2][192 * 64];  // 48 KB
  const int tid = threadIdx.x;
  const int l = tid & 63, lq = l & 15, qd = l >> 4;
  const int w = tid >> 6, wm = w >> 2, wn = w & 3;

  // XCD-aware 4x4-region swizzle over the 16x16 block grid
  const int wg = blockIdx.x;
  const int xcd = wg & 7, i5 = wg >> 3;        // i5 in [0,32)
  const int region = xcd * 2 + (i5 >> 4);      // [0,16)
  const int j = i5 & 15;
  const int bx = (region & 3) * 4 + (j & 3);   // n-tile [0,16)
  const int by = (region >> 2) * 4 + (j >> 2); // m-tile [0,16)
  const int m0 = by * 256, n0 = bx * 192;

  const bf16_t* Ag = xb + (size_t)m0 * E;
  const bf16_t* Bg = W3 + (size_t)n0 * E;

  f32x4 acc[8][3];
#pragma unroll
  for (int jj = 0; jj < 8; ++jj)
#pragma unroll
    for (int n = 0; n < 3; ++n) acc[jj][n] = (f32x4){0.f, 0.f, 0.f, 0.f};

  // prologue: B0,B1,B2,A0,A1 of tile 0 (steady-state issue order)
  stage_tile<64, 512>(Bg, E, Bs[0], tid);
  stage_tile<64, 512>(Bg + (size_t)64 * E, E, Bs[0] + 64 * 64, tid);
  stage_tile<64, 512>(Bg + (size_t)128 * E, E, Bs[0] + 128 * 64, tid);
  stage_A_chunk(Ag, 0, As[0], tid);
  stage_A_chunk(Ag, 1, As[0], tid);
  asm volatile("s_waitcnt vmcnt(2)" ::: "memory");
  __builtin_amdgcn_s_barrier();

#pragma unroll 1
  for (int g = 0; g < 16; ++g) {
    const int s = g & 1;
    const bf16_t* Al = As[s];
    const bf16_t* Bl = Bs[s];
    bf16_t* An = As[s ^ 1];
    bf16_t* Bn = Bs[s ^ 1];
    const bf16_t* Agn = Ag + (g + 1) * 64;
    const bf16_t* Bgn = Bg + (g + 1) * 64;
    const bool more = (g < 15);
    bf16x8 af[4], bfr[3];

    // ph0: A jj0-3 kk0 + B kk0; stage B0(t+1)
#pragma unroll
    for (int jj = 0; jj < 4; ++jj)
      af[jj] = read_frag(Al, wm * 128 + jj * 16 + lq, qd);
#pragma unroll
    for (int n = 0; n < 3; ++n)
      bfr[n] = read_frag(Bl, wn * 48 + n * 16 + lq, qd);
    if (more) stage_tile<64, 512>(Bgn, E, Bn, tid);
    __builtin_amdgcn_s_barrier();
    asm volatile("s_waitcnt lgkmcnt(0)" ::: "memory");
    __builtin_amdgcn_sched_barrier(0);
    __builtin_amdgcn_s_setprio(1);
#pragma unroll
    for (int jj = 0; jj < 4; ++jj)
#pragma unroll
      for (int n = 0; n < 3; ++n)
        acc[jj][n] = MFMA16(af[jj], bfr[n], acc[jj][n]);
    __builtin_amdgcn_s_setprio(0);
    if (more) asm volatile("s_waitcnt vmcnt(1)" ::: "memory");
    else      asm volatile("s_waitcnt vmcnt(0)" ::: "memory");
    __builtin_amdgcn_s_barrier();

    // ph1: A jj4-7 kk0 (reuse B kk0 frags); stage B1(t+1)
#pragma unroll
    for (int jj = 0; jj < 4; ++jj)
      af[jj] = read_frag(Al, wm * 128 + (4 + jj) * 16 + lq, qd);
    if (more) stage_tile<64, 512>(Bgn + (size_t)64 * E, E, Bn + 64 * 64, tid);
    __builtin_amdgcn_s_barrier();
    asm volatile("s_waitcnt lgkmcnt(0)" ::: "memory");
    __builtin_amdgcn_sched_barrier(0);
    __builtin_amdgcn_s_setprio(1);
#pragma unroll
    for (int jj = 0; jj < 4; ++jj)
#pragma unroll
      for (int n = 0; n < 3; ++n)
        acc[4 + jj][n] = MFMA16(af[jj], bfr[n], acc[4 + jj][n]);
    __builtin_amdgcn_s_setprio(0);
    __builtin_amdgcn_s_barrier();

    // ph2: A jj0-3 kk1 + B kk1; stage B2(t+1) + A0(t+1)
#pragma unroll
    for (int jj = 0; jj < 4; ++jj)
      af[jj] = read_frag(Al, wm * 128 + jj * 16 + lq, 4 + qd);
#pragma unroll
    for (int n = 0; n < 3; ++n)
      bfr[n] = read_frag(Bl, wn * 48 + n * 16 + lq, 4 + qd);
    if (more) {
      stage_tile<64, 512>(Bgn + (size_t)128 * E, E, Bn + 128 * 64, tid);
      stage_A_chunk(Agn, 0, An, tid);
    }
    __builtin_amdgcn_s_barrier();
    asm volatile("s_waitcnt lgkmcnt(0)" ::: "memory");
    __builtin_amdgcn_sched_barrier(0);
    __builtin_amdgcn_s_setprio(1);
#pragma unroll
    for (int jj = 0; jj < 4; ++jj)
#pragma unroll
      for (int n = 0; n < 3; ++n)
        acc[jj][n] = MFMA16(af[jj], bfr[n], acc[jj][n]);
    __builtin_amdgcn_s_setprio(0);
    __builtin_amdgcn_s_barrier();

    // ph3: A jj4-7 kk1; stage A1(t+1)
#pragma unroll
    for (int jj = 0; jj < 4; ++jj)
      af[jj] = read_frag(Al, wm * 128 + (4 + jj) * 16 + lq, 4 + qd);
    if (more) stage_A_chunk(Agn, 1, An, tid);
    __builtin_amdgcn_s_barrier();
    asm volatile("s_waitcnt lgkmcnt(0)" ::: "memory");
    __builtin_amdgcn_sched_barrier(0);
    __builtin_amdgcn_s_setprio(1);
#pragma unroll
    for (int jj = 0; jj < 4; ++jj)
#pragma unroll
      for (int n = 0; n < 3; ++n)
        acc[4 + jj][n] = MFMA16(af[jj], bfr[n], acc[4 + jj][n]);
    __builtin_amdgcn_s_setprio(0);
    if (more) asm volatile("s_waitcnt vmcnt(2)" ::: "memory");
    __builtin_amdgcn_s_barrier();
  }

  // epilogue: per-column routing (192-col tile may span Q/K/V)
#pragma unroll
  for (int n = 0; n < 3; ++n) {
    const int col = n0 + wn * 48 + n * 16 + lq;
    const int mat = col >> 10, cc = col & 1023;
    const float bvv = (mat == 0 ? bq : mat == 1 ? bk : bv)[cc];
    if (mat < 2) {
      const float sc = (mat == 0) ? 0.18033688011112043f : 1.0f;  // log2(e)/8
      bf16_t* Out = QKb + (size_t)mat * ((size_t)M * E);
#pragma unroll
      for (int jj = 0; jj < 8; ++jj)
#pragma unroll
        for (int r = 0; r < 4; ++r) {
          const int row = m0 + wm * 128 + jj * 16 + qd * 4 + r;
          Out[(size_t)row * E + cc] = (bf16_t)((acc[jj][n][r] + bvv) * sc);
        }
    } else {
      // V -> VT sigma-permuted transpose; 4 r-rows -> one bf16x4 store
      const int d = cc & 63, hh = cc >> 6;
#pragma unroll
      for (int jj = 0; jj < 8; ++jj) {
        const int row = m0 + wm * 128 + jj * 16 + qd * 4;  // r=0 base
        const int bb_ = row >> 11;           // batch
        const int s_loc = row & (S - 1);
        const int sl = s_loc & 63, s0 = s_loc & ~63;
        const int a = sl >> 4, b4 = (sl >> 2) & 3;
        const int pb = (a >> 1) * 32 + b4 * 8 + (a & 1) * 4;
        bf16x4 vv;
#pragma unroll
        for (int r = 0; r < 4; ++r) vv[r] = (bf16_t)(acc[jj][n][r] + bvv);
        *(bf16x4*)&VT[((size_t)((bb_ * 16 + hh) * 64 + d)) * S + s0 + pb] = vv;
      }
    }
  }
}

// ---------------------------------------------------------------------------
// output projection, v2 (kept): 64x128 tiles, tri-buffered counted-vmcnt.
// ---------------------------------------------------------------------------
__global__ __launch_bounds__(256, 2) void oproj_gemm_kernel(
    const bf16_t* __restrict__ Ob, const bf16_t* __restrict__ wo,
    const float* __restrict__ bo, float* __restrict__ out) {
  __shared__ __align__(16) bf16_t As[3][64 * 64];    // 24 KB
  __shared__ __align__(16) bf16_t Bs[3][128 * 64];   // 48 KB
  const int tid = threadIdx.x;
  const int w = tid >> 6, l = tid & 63, lq = l & 15, qd = l >> 4;
  const int wr = (w >> 1) * 32, wc = (w & 1) * 64;

  // XCD swizzle: 512 blocks = 8 XCD x (8 m-rows x 8 n-cols)
  const int swz = (blockIdx.x & 7) * 64 + (blockIdx.x >> 3);
  const int m0 = (swz >> 3) * 64, n0 = (swz & 7) * 128;
  const bf16_t* Ag = Ob + (size_t)m0 * E;
  const bf16_t* Bg = wo + (size_t)n0 * E;

  f32x4 acc[2][4];
#pragma unroll
  for (int i = 0; i < 2; ++i)
#pragma unroll
    for (int jj = 0; jj < 4; ++jj) acc[i][jj] = (f32x4){0.f, 0.f, 0.f, 0.f};

  // prologue: stage tiles 0 and 1
  stage_tile<64, 256>(Ag, E, As[0], tid);
  stage_tile<128, 256>(Bg, E, Bs[0], tid);
  stage_tile<64, 256>(Ag + 64, E, As[1], tid);
  stage_tile<128, 256>(Bg + 64, E, Bs[1], tid);
  asm volatile("s_waitcnt vmcnt(6)" ::: "memory");  // tile 0 landed (own)

  int rd = 0, stg = 2;  // read slot = kt%3; stage slot = (kt+2)%3
#pragma unroll 1
  for (int kt = 0; kt < 16; ++kt) {
    __builtin_amdgcn_s_barrier();  // all waves: tile kt landed (gate last
                                   // iter) AND done reading slot stg
    if (kt < 14) {
      stage_tile<64, 256>(Ag + (kt + 2) * 64, E, As[stg], tid);
      stage_tile<128, 256>(Bg + (kt + 2) * 64, E, Bs[stg], tid);
    }
    const bf16_t* Al = As[rd];
    const bf16_t* Bl = Bs[rd];
#pragma unroll
    for (int ks = 0; ks < 2; ++ks) {
      bf16x8 af[2], bw[4];
#pragma unroll
      for (int mi = 0; mi < 2; ++mi)
        af[mi] = read_frag(Al, wr + mi * 16 + lq, ks * 4 + qd);
#pragma unroll
      for (int ni = 0; ni < 4; ++ni)
        bw[ni] = read_frag(Bl, wc + ni * 16 + lq, ks * 4 + qd);
#pragma unroll
      for (int mi = 0; mi < 2; ++mi)
#pragma unroll
        for (int ni = 0; ni < 4; ++ni)
          acc[mi][ni] = MFMA16(af[mi], bw[ni], acc[mi][ni]);
    }
    if (kt < 14)       asm volatile("s_waitcnt vmcnt(6)" ::: "memory");
    else if (kt == 14) asm volatile("s_waitcnt vmcnt(0)" ::: "memory");
    stg = rd;
    rd = (rd + 1 == 3) ? 0 : rd + 1;
  }

#pragma unroll
  for (int ni = 0; ni < 4; ++ni) {
    const int col = n0 + wc + ni * 16 + lq;
    const float bvv = bo[col];
#pragma unroll
    for (int mi = 0; mi < 2; ++mi)
#pragma unroll
      for (int r = 0; r < 4; ++r) {
        const int row = m0 + wr + mi * 16 + qd * 4 + r;
        out[(size_t)row * E + col] = acc[mi][ni][r] + bvv;
      }
  }
}

// ---------------------------------------------------------------------------
// causal flash attention v19 = v16 + COUNTED-VMCNT staging (T4 applied to
// attn; removes the per-iter __syncthreads vmcnt(0) drain convoy).
// Per iter: { lgkmcnt(0); s_barrier (readers of overwrite-slots done);
//   issue 8 glds (tile kt+1); vmcnt(8) (tile kt's own 8 landed, new 8 fly);
//   s_barrier (block-wide: tile kt visible); compute }.
// vmcnt(0) only on the block's FINAL iteration (nothing staged there).
// Everything else = v16: operand-swapped S^T=K*Q^T; sigma-permuted VT;
// KVBLK=128, 17 tiles per pair {31-p,p}; PV(kt-1) overlaps softmax; V tri-buf
// + K dbuf (80 KB, 2 blocks/CU); ones-MFMA rowsum; cvt_pk P-packing; no-max
// softmax (Q pre-scaled by log2e/8); XCD map g=bid&7 -> bh [4g,4g+4).
// ---------------------------------------------------------------------------
__global__ __launch_bounds__(256, 2) void attn_kernel(
    const bf16_t* __restrict__ Q, const bf16_t* __restrict__ K,
    const bf16_t* __restrict__ VT, bf16_t* __restrict__ O) {
  __shared__ __align__(16) bf16_t Ks[2][128 * 64];  // K dbuf, 32 KB
  __shared__ __align__(16) bf16_t Vt[3][64 * 128];  // V tri-buf, 48 KB

  const int tid = threadIdx.x;
  const int w = tid >> 6, l = tid & 63;
  const int lq = l & 15, qd = l >> 4;
  const int bid = blockIdx.x;
  const int g = bid & 7, t = bid >> 3;  // 64 blocks per XCD-group
  const int bh = g * 4 + (t & 3);       // 4 bh per XCD-group: L2-resident K/VT
  const int p = t >> 2;                 // pair index: q-tiles {31-p, p}
  const int b = bh >> 4, h = bh & 15;
  const size_t rowbase = (size_t)b * S;
  const bf16_t* Kg = K + rowbase * E + h * 64;
  const bf16_t* Vg = VT + (size_t)bh * 64 * S;

  bf16x8 ones;
#pragma unroll
  for (int jj = 0; jj < 8; ++jj) ones[jj] = (bf16_t)1.0f;

  // prefetch 128-key tile 0 into K slot 0 / V slot 0 (8 loads/thread)
  stage_tile<128, 256>(Kg, E, Ks[0], tid);
  stage_v128(Vg, S, Vt[0], tid);
  int cb = 0, vcur = 0;

#pragma unroll 1
  for (int seg = 0; seg < 2; ++seg) {
    const int qt = seg ? p : 31 - p;    // heavy q-tile first
    const int T = (qt + 2) >> 1;        // 128-key tiles this segment
    const int qr = qt * 64 + w * 16;    // wave rows [qr, qr+16)
    const int qg = qr + lq;             // this lane's query row

    bf16x8 aq[2];
#pragma unroll
    for (int ks = 0; ks < 2; ++ks)
      aq[ks] = *(const bf16x8*)(Q + (rowbase + qr + lq) * E + h * 64 +
                                ks * 32 + qd * 8);

    f32x4 oacc[4];
#pragma unroll
    for (int nt = 0; nt < 4; ++nt) oacc[nt] = (f32x4){0.f, 0.f, 0.f, 0.f};
    f32x4 osum = (f32x4){0.f, 0.f, 0.f, 0.f};
    bf16x8 ap_prev[4];                   // P frags of tile kt-1 (128 keys)
    int vprev = vcur;

    // PV of the previous tile: 16 oacc-MFMA + 4 ones-MFMA
    auto do_pv = [&](const bf16_t* Vp) {
#pragma unroll
      for (int c = 0; c < 4; ++c) {
        bf16x8 bv[4];
#pragma unroll
        for (int nt = 0; nt < 4; ++nt)
          bv[nt] = read_v128(Vp, nt * 16 + lq, c * 4 + qd);
#pragma unroll
        for (int nt = 0; nt < 4; ++nt)
          oacc[nt] = MFMA16(ap_prev[c], bv[nt], oacc[nt]);
        osum = MFMA16(ap_prev[c], ones, osum);
      }
    };

    for (int kt = 0; kt < T; ++kt) {
      // barrier 1: all waves' ds_reads of the slots about to be overwritten
      // are retired (their lgkm waits executed before last iter's MFMAs;
      // lgkmcnt(0) is cheap insurance).
      asm volatile("s_waitcnt lgkmcnt(0)" ::: "memory");
      __builtin_amdgcn_s_barrier();

      const int vnext = (vcur + 1 == 3) ? 0 : vcur + 1;
      const bool staged = (kt < T - 1) || (seg == 0);
      if (kt < T - 1) {                 // stage tile kt+1
        const int kn = (kt + 1) * 128;
        stage_tile<128, 256>(Kg + (size_t)kn * E, E, Ks[cb ^ 1], tid);
        stage_v128(Vg + kn, S, Vt[vnext], tid);
      } else if (seg == 0) {            // handoff: stage segment B's tile 0
        stage_tile<128, 256>(Kg, E, Ks[cb ^ 1], tid);
        stage_v128(Vg, S, Vt[vnext], tid);
      }
      // gate: MY 8 loads for tile kt (issued last iter) landed; the 8 just
      // issued may stay in flight (T4: never drain to 0 mid-loop).
      if (staged) asm volatile("s_waitcnt vmcnt(8)" ::: "memory");
      else        asm volatile("s_waitcnt vmcnt(0)" ::: "memory");
      // barrier 2: joins all waves' gates -> tile kt fully in LDS block-wide.
      __builtin_amdgcn_s_barrier();

      const bf16_t* Kc = Ks[cb];
      const int k0 = kt * 128;
      const bool needmask = (kt == T - 1);

      // ---- S^T = K * Q^T : 16 MFMA; lane holds q=lq, keys nt*16+qd*4+r ----
      f32x4 sacc[8];
#pragma unroll
      for (int nt = 0; nt < 8; ++nt) sacc[nt] = (f32x4){0.f, 0.f, 0.f, 0.f};
      __builtin_amdgcn_s_setprio(1);
#pragma unroll
      for (int ks = 0; ks < 2; ++ks) {
        bf16x8 bk[8];
#pragma unroll
        for (int nt = 0; nt < 8; ++nt)
          bk[nt] = read_frag(Kc, nt * 16 + lq, ks * 4 + qd);
#pragma unroll
        for (int nt = 0; nt < 8; ++nt)
          sacc[nt] = MFMA16(bk[nt], aq[ks], sacc[nt]);
      }
      // ---- PV of tile kt-1 (independent; overlaps softmax below) ----
      if (kt > 0) do_pv(Vt[vprev]);
      __builtin_amdgcn_s_setprio(0);

      // ---- softmax: exp2 in f32 (mask on f32), pack via v_cvt_pk_bf16_f32 ----
      float pvf[8][4];
      if (needmask) {
#pragma unroll
        for (int nt = 0; nt < 8; ++nt)
#pragma unroll
          for (int r = 0; r < 4; ++r) {
            float pv = __builtin_amdgcn_exp2f(sacc[nt][r]);
            const int kg = k0 + nt * 16 + qd * 4 + r;
            pvf[nt][r] = (kg > qg) ? 0.f : pv;
          }
      } else {
#pragma unroll
        for (int nt = 0; nt < 8; ++nt)
#pragma unroll
          for (int r = 0; r < 4; ++r)
            pvf[nt][r] = __builtin_amdgcn_exp2f(sacc[nt][r]);
      }
#pragma unroll
      for (int c = 0; c < 4; ++c) {
        union { unsigned u[4]; bf16x8 v; } pk;
        pk.u[0] = cvtpk(pvf[2 * c][0], pvf[2 * c][1]);
        pk.u[1] = cvtpk(pvf[2 * c][2], pvf[2 * c][3]);
        pk.u[2] = cvtpk(pvf[2 * c + 1][0], pvf[2 * c + 1][1]);
        pk.u[3] = cvtpk(pvf[2 * c + 1][2], pvf[2 * c + 1][3]);
        ap_prev[c] = pk.v;
      }
      vprev = vcur;
      vcur = vnext;
      cb ^= 1;
    }
    // epilogue: PV of the segment's last tile
    do_pv(Vt[vprev]);

    // normalize + store: osum[r] = rowsum for q-row qd*4+r = C-layout rows
    float rinv[4];
#pragma unroll
    for (int r = 0; r < 4; ++r) rinv[r] = 1.0f / osum[r];
#pragma unroll
    for (int nt = 0; nt < 4; ++nt)
#pragma unroll
      for (int r = 0; r < 4; ++r) {
        const int qgw = qr + qd * 4 + r;
        O[(rowbase + qgw) * E + h * 64 + nt * 16 + lq] =
            (bf16_t)(oacc[nt][r] * rinv[r]);
      }
  }
}

// ---------------------------------------------------------------------------
// launch
// ---------------------------------------------------------------------------
extern "C" void kernel_launch(void* const* d_in, const int* in_sizes, int n_in,
                              void* d_out, int out_size, void* d_ws, size_t ws_size,
                              hipStream_t stream) {
  const float* x  = (const float*)d_in[0];
  const float* Wq = (const float*)d_in[1];
  const float* bq = (const float*)d_in[2];
  const float* Wk = (const float*)d_in[3];
  const float* bk = (const float*)d_in[4];
  const float* Wv = (const float*)d_in[5];
  const float* bv = (const float*)d_in[6];
  const float* Wo = (const float*)d_in[7];
  const float* bo = (const float*)d_in[8];
  float* out = (float*)d_out;

  unsigned char* ws = (unsigned char*)d_ws;
  constexpr size_t MB = 1ull << 20;
  bf16_t* xb  = (bf16_t*)(ws + 0 * MB);   // 8 MB; reused as Ob after qkv
  bf16_t* wqb = (bf16_t*)(ws + 8 * MB);   // wq/wk/wv contiguous [3072][1024]
  bf16_t* wkb = (bf16_t*)(ws + 10 * MB);
  bf16_t* wvb = (bf16_t*)(ws + 12 * MB);
  bf16_t* wob = (bf16_t*)(ws + 14 * MB);
  bf16_t* Qb  = (bf16_t*)(ws + 16 * MB);  // Q/K contiguous [2][4096][1024]
  bf16_t* VT  = (bf16_t*)(ws + 40 * MB);  // [32 bh][64 d][2048 s, sigma-perm per 64]
  bf16_t* Ob  = xb;                       // xb dead after qkv

  cvt_all_kernel<<<4096, 256, 0, stream>>>(
      x, Wq, Wk, Wv, Wo, xb, wqb, wkb, wvb, wob);

  qkv8_kernel<<<256, 512, 0, stream>>>(xb, wqb, bq, bk, bv, Qb, VT);

  attn_kernel<<<512, 256, 0, stream>>>(Qb, Qb + (size_t)M * E, VT, Ob);

  oproj_gemm_kernel<<<512, 256, 0, stream>>>(Ob, wob, bo, out);
}

// Round 13
// 168.774 us; speedup vs baseline: 1.0060x; 1.0060x over previous
//
#include <hip/hip_runtime.h>
#include <hip/hip_bf16.h>

typedef __bf16 bf16_t;
typedef __bf16 bf16x8 __attribute__((ext_vector_type(8)));
typedef __bf16 bf16x4 __attribute__((ext_vector_type(4)));
typedef float  f32x4  __attribute__((ext_vector_type(4)));

#define MFMA16(a, b, c) __builtin_amdgcn_mfma_f32_16x16x32_bf16((a), (b), (c), 0, 0, 0)

constexpr int E  = 1024;
constexpr int S  = 2048;
constexpr int H  = 16;
constexpr int M  = 4096;  // B*S

// ---------------------------------------------------------------------------
// async global->LDS 16B (wave-uniform LDS base + lane*16)
// ---------------------------------------------------------------------------
__device__ __forceinline__ void glds16(const bf16_t* src, bf16_t* dst) {
  __builtin_amdgcn_global_load_lds(
      (const __attribute__((address_space(1))) void*)src,
      (__attribute__((address_space(3))) void*)dst, 16, 0, 0);
}

// Stage a [ROWS x 64] bf16 tile (global row stride gld) into LDS, XOR-swizzled.
// NT = participating threads (pass a local tid in [0,NT)).
template <int ROWS, int NT>
__device__ __forceinline__ void stage_tile(const bf16_t* g, int gld,
                                           bf16_t* lds, int tid) {
  const int w = tid >> 6, l = tid & 63;
#pragma unroll
  for (int i = 0; i < ROWS * 8 / NT; ++i) {
    const int c = i * NT + w * 64 + l;
    const int row = c >> 3;
    const int gch = (c & 7) ^ (row & 7);
    glds16(g + (size_t)row * gld + gch * 8, lds + (size_t)(i * NT + w * 64) * 8);
  }
}

// Stage a [64 x 128] bf16 tile (row stride gld) into LDS, XOR-swizzled in
// 16B chunks within each row. NT=256: 4 glds/thread.
__device__ __forceinline__ void stage_v128(const bf16_t* g, int gld,
                                           bf16_t* lds, int tid) {
#pragma unroll
  for (int i = 0; i < 4; ++i) {
    const int c = i * 256 + tid;          // [0,1024)
    const int row = c >> 4, col16 = c & 15;
    const int gch = col16 ^ (row & 7);
    glds16(g + (size_t)row * gld + gch * 8, lds + (size_t)c * 8);
  }
}

// Stage interleaved A-chunk c of a 256-row tile (qkv kernel helper).
__device__ __forceinline__ void stage_A_chunk(const bf16_t* g, int c,
                                              bf16_t* lds, int tid) {
  const int w = tid >> 6, l = tid & 63;
#pragma unroll
  for (int i = 0; i < 2; ++i) {
    const int gc = i * 512 + w * 64 + l;      // [0,1024)
    const int row_l = gc >> 3;                // [0,128)
    const int col8 = gc & 7;
    const int h = row_l >> 6, rr = row_l & 63;
    const int row = h * 128 + c * 64 + rr;    // LDS == global row
    const int gch = col8 ^ (row & 7);
    glds16(g + (size_t)row * E + gch * 8, lds + ((size_t)row * 8 + col8) * 8);
  }
}

// Read an 8-elem k-chunk (kc in [0,8)) of row `row` from a swizzled [R x 64] tile.
__device__ __forceinline__ bf16x8 read_frag(const bf16_t* lds, int row, int kc) {
  return *(const bf16x8*)(lds + (size_t)((row << 3) + (kc ^ (row & 7))) * 8);
}

// Read an 8-elem chunk (kc in [0,16)) of row `row` from a swizzled [64 x 128] tile.
__device__ __forceinline__ bf16x8 read_v128(const bf16_t* lds, int row, int kc) {
  return *(const bf16x8*)(lds + (size_t)((row << 4) + (kc ^ (row & 7))) * 8);
}

// pack 2 f32 -> 1 u32 of 2 bf16 (lo=a, hi=b), one full-rate inst (T12)
__device__ __forceinline__ unsigned cvtpk(float a, float b) {
  unsigned r;
  asm("v_cvt_pk_bf16_f32 %0, %1, %2" : "=v"(r) : "v"(a), "v"(b));
  return r;
}

// ---------------------------------------------------------------------------
// fused fp32->bf16 conversion, v2: 32B read / 16B write per thread.
// ---------------------------------------------------------------------------
__global__ void cvt_all_kernel(const float* __restrict__ x,
                               const float* __restrict__ w0, const float* __restrict__ w1,
                               const float* __restrict__ w2, const float* __restrict__ w3,
                               bf16_t* __restrict__ xb,
                               bf16_t* __restrict__ o0, bf16_t* __restrict__ o1,
                               bf16_t* __restrict__ o2, bf16_t* __restrict__ o3) {
  const int bid = blockIdx.x;
  const float* s;
  bf16_t* d;
  int idx;
  if (bid < 2048) {
    s = x; d = xb; idx = bid * 256 + threadIdx.x;
  } else {
    const int seg = (bid - 2048) >> 9;
    s = seg == 0 ? w0 : seg == 1 ? w1 : seg == 2 ? w2 : w3;
    d = seg == 0 ? o0 : seg == 1 ? o1 : seg == 2 ? o2 : o3;
    idx = ((bid - 2048) & 511) * 256 + threadIdx.x;
  }
  float4 v0 = ((const float4*)s)[idx * 2];
  float4 v1 = ((const float4*)s)[idx * 2 + 1];
  bf16x8 o;
  o[0] = (bf16_t)v0.x; o[1] = (bf16_t)v0.y; o[2] = (bf16_t)v0.z; o[3] = (bf16_t)v0.w;
  o[4] = (bf16_t)v1.x; o[5] = (bf16_t)v1.y; o[6] = (bf16_t)v1.z; o[7] = (bf16_t)v1.w;
  ((bf16x8*)d)[idx] = o;
}

// ---------------------------------------------------------------------------
// fused QKV projection, v5 (kept): counted-vmcnt 4-phase schedule at 256x192,
// grid 16x16 = 256 blocks (all CUs). W fused [3072][1024]; Q/K row-major;
// V -> sigma-permuted VT. Q PRE-SCALED by log2(e)/8.
// ---------------------------------------------------------------------------
__global__ __launch_bounds__(512, 1) void qkv8_kernel(
    const bf16_t* __restrict__ xb, const bf16_t* __restrict__ W3,
    const float* __restrict__ bq, const float* __restrict__ bk,
    const float* __restrict__ bv, bf16_t* __restrict__ QKb,
    bf16_t* __restrict__ VT) {
  __shared__ __align__(16) bf16_t As[2][256 * 64];  // 64 KB
  __shared__ __align__(16) bf16_t Bs[2][192 * 64];  // 48 KB
  const int tid = threadIdx.x;
  const int l = tid & 63, lq = l & 15, qd = l >> 4;
  const int w = tid >> 6, wm = w >> 2, wn = w & 3;

  // XCD-aware 4x4-region swizzle over the 16x16 block grid
  const int wg = blockIdx.x;
  const int xcd = wg & 7, i5 = wg >> 3;        // i5 in [0,32)
  const int region = xcd * 2 + (i5 >> 4);      // [0,16)
  const int j = i5 & 15;
  const int bx = (region & 3) * 4 + (j & 3);   // n-tile [0,16)
  const int by = (region >> 2) * 4 + (j >> 2); // m-tile [0,16)
  const int m0 = by * 256, n0 = bx * 192;

  const bf16_t* Ag = xb + (size_t)m0 * E;
  const bf16_t* Bg = W3 + (size_t)n0 * E;

  f32x4 acc[8][3];
#pragma unroll
  for (int jj = 0; jj < 8; ++jj)
#pragma unroll
    for (int n = 0; n < 3; ++n) acc[jj][n] = (f32x4){0.f, 0.f, 0.f, 0.f};

  // prologue: B0,B1,B2,A0,A1 of tile 0 (steady-state issue order)
  stage_tile<64, 512>(Bg, E, Bs[0], tid);
  stage_tile<64, 512>(Bg + (size_t)64 * E, E, Bs[0] + 64 * 64, tid);
  stage_tile<64, 512>(Bg + (size_t)128 * E, E, Bs[0] + 128 * 64, tid);
  stage_A_chunk(Ag, 0, As[0], tid);
  stage_A_chunk(Ag, 1, As[0], tid);
  asm volatile("s_waitcnt vmcnt(2)" ::: "memory");
  __builtin_amdgcn_s_barrier();

#pragma unroll 1
  for (int g = 0; g < 16; ++g) {
    const int s = g & 1;
    const bf16_t* Al = As[s];
    const bf16_t* Bl = Bs[s];
    bf16_t* An = As[s ^ 1];
    bf16_t* Bn = Bs[s ^ 1];
    const bf16_t* Agn = Ag + (g + 1) * 64;
    const bf16_t* Bgn = Bg + (g + 1) * 64;
    const bool more = (g < 15);
    bf16x8 af[4], bfr[3];

    // ph0: A jj0-3 kk0 + B kk0; stage B0(t+1)
#pragma unroll
    for (int jj = 0; jj < 4; ++jj)
      af[jj] = read_frag(Al, wm * 128 + jj * 16 + lq, qd);
#pragma unroll
    for (int n = 0; n < 3; ++n)
      bfr[n] = read_frag(Bl, wn * 48 + n * 16 + lq, qd);
    if (more) stage_tile<64, 512>(Bgn, E, Bn, tid);
    __builtin_amdgcn_s_barrier();
    asm volatile("s_waitcnt lgkmcnt(0)" ::: "memory");
    __builtin_amdgcn_sched_barrier(0);
    __builtin_amdgcn_s_setprio(1);
#pragma unroll
    for (int jj = 0; jj < 4; ++jj)
#pragma unroll
      for (int n = 0; n < 3; ++n)
        acc[jj][n] = MFMA16(af[jj], bfr[n], acc[jj][n]);
    __builtin_amdgcn_s_setprio(0);
    if (more) asm volatile("s_waitcnt vmcnt(1)" ::: "memory");
    else      asm volatile("s_waitcnt vmcnt(0)" ::: "memory");
    __builtin_amdgcn_s_barrier();

    // ph1: A jj4-7 kk0 (reuse B kk0 frags); stage B1(t+1)
#pragma unroll
    for (int jj = 0; jj < 4; ++jj)
      af[jj] = read_frag(Al, wm * 128 + (4 + jj) * 16 + lq, qd);
    if (more) stage_tile<64, 512>(Bgn + (size_t)64 * E, E, Bn + 64 * 64, tid);
    __builtin_amdgcn_s_barrier();
    asm volatile("s_waitcnt lgkmcnt(0)" ::: "memory");
    __builtin_amdgcn_sched_barrier(0);
    __builtin_amdgcn_s_setprio(1);
#pragma unroll
    for (int jj = 0; jj < 4; ++jj)
#pragma unroll
      for (int n = 0; n < 3; ++n)
        acc[4 + jj][n] = MFMA16(af[jj], bfr[n], acc[4 + jj][n]);
    __builtin_amdgcn_s_setprio(0);
    __builtin_amdgcn_s_barrier();

    // ph2: A jj0-3 kk1 + B kk1; stage B2(t+1) + A0(t+1)
#pragma unroll
    for (int jj = 0; jj < 4; ++jj)
      af[jj] = read_frag(Al, wm * 128 + jj * 16 + lq, 4 + qd);
#pragma unroll
    for (int n = 0; n < 3; ++n)
      bfr[n] = read_frag(Bl, wn * 48 + n * 16 + lq, 4 + qd);
    if (more) {
      stage_tile<64, 512>(Bgn + (size_t)128 * E, E, Bn + 128 * 64, tid);
      stage_A_chunk(Agn, 0, An, tid);
    }
    __builtin_amdgcn_s_barrier();
    asm volatile("s_waitcnt lgkmcnt(0)" ::: "memory");
    __builtin_amdgcn_sched_barrier(0);
    __builtin_amdgcn_s_setprio(1);
#pragma unroll
    for (int jj = 0; jj < 4; ++jj)
#pragma unroll
      for (int n = 0; n < 3; ++n)
        acc[jj][n] = MFMA16(af[jj], bfr[n], acc[jj][n]);
    __builtin_amdgcn_s_setprio(0);
    __builtin_amdgcn_s_barrier();

    // ph3: A jj4-7 kk1; stage A1(t+1)
#pragma unroll
    for (int jj = 0; jj < 4; ++jj)
      af[jj] = read_frag(Al, wm * 128 + (4 + jj) * 16 + lq, 4 + qd);
    if (more) stage_A_chunk(Agn, 1, An, tid);
    __builtin_amdgcn_s_barrier();
    asm volatile("s_waitcnt lgkmcnt(0)" ::: "memory");
    __builtin_amdgcn_sched_barrier(0);
    __builtin_amdgcn_s_setprio(1);
#pragma unroll
    for (int jj = 0; jj < 4; ++jj)
#pragma unroll
      for (int n = 0; n < 3; ++n)
        acc[4 + jj][n] = MFMA16(af[jj], bfr[n], acc[4 + jj][n]);
    __builtin_amdgcn_s_setprio(0);
    if (more) asm volatile("s_waitcnt vmcnt(2)" ::: "memory");
    __builtin_amdgcn_s_barrier();
  }

  // epilogue: per-column routing (192-col tile may span Q/K/V)
#pragma unroll
  for (int n = 0; n < 3; ++n) {
    const int col = n0 + wn * 48 + n * 16 + lq;
    const int mat = col >> 10, cc = col & 1023;
    const float bvv = (mat == 0 ? bq : mat == 1 ? bk : bv)[cc];
    if (mat < 2) {
      const float sc = (mat == 0) ? 0.18033688011112043f : 1.0f;  // log2(e)/8
      bf16_t* Out = QKb + (size_t)mat * ((size_t)M * E);
#pragma unroll
      for (int jj = 0; jj < 8; ++jj)
#pragma unroll
        for (int r = 0; r < 4; ++r) {
          const int row = m0 + wm * 128 + jj * 16 + qd * 4 + r;
          Out[(size_t)row * E + cc] = (bf16_t)((acc[jj][n][r] + bvv) * sc);
        }
    } else {
      // V -> VT sigma-permuted transpose; 4 r-rows -> one bf16x4 store
      const int d = cc & 63, hh = cc >> 6;
#pragma unroll
      for (int jj = 0; jj < 8; ++jj) {
        const int row = m0 + wm * 128 + jj * 16 + qd * 4;  // r=0 base
        const int bb_ = row >> 11;           // batch
        const int s_loc = row & (S - 1);
        const int sl = s_loc & 63, s0 = s_loc & ~63;
        const int a = sl >> 4, b4 = (sl >> 2) & 3;
        const int pb = (a >> 1) * 32 + b4 * 8 + (a & 1) * 4;
        bf16x4 vv;
#pragma unroll
        for (int r = 0; r < 4; ++r) vv[r] = (bf16_t)(acc[jj][n][r] + bvv);
        *(bf16x4*)&VT[((size_t)((bb_ * 16 + hh) * 64 + d)) * S + s0 + pb] = vv;
      }
    }
  }
}

// ---------------------------------------------------------------------------
// output projection, v2 (kept): 64x128 tiles, tri-buffered counted-vmcnt.
// ---------------------------------------------------------------------------
__global__ __launch_bounds__(256, 2) void oproj_gemm_kernel(
    const bf16_t* __restrict__ Ob, const bf16_t* __restrict__ wo,
    const float* __restrict__ bo, float* __restrict__ out) {
  __shared__ __align__(16) bf16_t As[3][64 * 64];    // 24 KB
  __shared__ __align__(16) bf16_t Bs[3][128 * 64];   // 48 KB
  const int tid = threadIdx.x;
  const int w = tid >> 6, l = tid & 63, lq = l & 15, qd = l >> 4;
  const int wr = (w >> 1) * 32, wc = (w & 1) * 64;

  // XCD swizzle: 512 blocks = 8 XCD x (8 m-rows x 8 n-cols)
  const int swz = (blockIdx.x & 7) * 64 + (blockIdx.x >> 3);
  const int m0 = (swz >> 3) * 64, n0 = (swz & 7) * 128;
  const bf16_t* Ag = Ob + (size_t)m0 * E;
  const bf16_t* Bg = wo + (size_t)n0 * E;

  f32x4 acc[2][4];
#pragma unroll
  for (int i = 0; i < 2; ++i)
#pragma unroll
    for (int jj = 0; jj < 4; ++jj) acc[i][jj] = (f32x4){0.f, 0.f, 0.f, 0.f};

  // prologue: stage tiles 0 and 1
  stage_tile<64, 256>(Ag, E, As[0], tid);
  stage_tile<128, 256>(Bg, E, Bs[0], tid);
  stage_tile<64, 256>(Ag + 64, E, As[1], tid);
  stage_tile<128, 256>(Bg + 64, E, Bs[1], tid);
  asm volatile("s_waitcnt vmcnt(6)" ::: "memory");  // tile 0 landed (own)

  int rd = 0, stg = 2;  // read slot = kt%3; stage slot = (kt+2)%3
#pragma unroll 1
  for (int kt = 0; kt < 16; ++kt) {
    __builtin_amdgcn_s_barrier();  // all waves: tile kt landed (gate last
                                   // iter) AND done reading slot stg
    if (kt < 14) {
      stage_tile<64, 256>(Ag + (kt + 2) * 64, E, As[stg], tid);
      stage_tile<128, 256>(Bg + (kt + 2) * 64, E, Bs[stg], tid);
    }
    const bf16_t* Al = As[rd];
    const bf16_t* Bl = Bs[rd];
#pragma unroll
    for (int ks = 0; ks < 2; ++ks) {
      bf16x8 af[2], bw[4];
#pragma unroll
      for (int mi = 0; mi < 2; ++mi)
        af[mi] = read_frag(Al, wr + mi * 16 + lq, ks * 4 + qd);
#pragma unroll
      for (int ni = 0; ni < 4; ++ni)
        bw[ni] = read_frag(Bl, wc + ni * 16 + lq, ks * 4 + qd);
#pragma unroll
      for (int mi = 0; mi < 2; ++mi)
#pragma unroll
        for (int ni = 0; ni < 4; ++ni)
          acc[mi][ni] = MFMA16(af[mi], bw[ni], acc[mi][ni]);
    }
    if (kt < 14)       asm volatile("s_waitcnt vmcnt(6)" ::: "memory");
    else if (kt == 14) asm volatile("s_waitcnt vmcnt(0)" ::: "memory");
    stg = rd;
    rd = (rd + 1 == 3) ? 0 : rd + 1;
  }

#pragma unroll
  for (int ni = 0; ni < 4; ++ni) {
    const int col = n0 + wc + ni * 16 + lq;
    const float bvv = bo[col];
#pragma unroll
    for (int mi = 0; mi < 2; ++mi)
#pragma unroll
      for (int r = 0; r < 4; ++r) {
        const int row = m0 + wr + mi * 16 + qd * 4 + r;
        out[(size_t)row * E + col] = acc[mi][ni][r] + bvv;
      }
  }
}

// ---------------------------------------------------------------------------
// causal flash attention v20 = v16 (R11 winner, REVERTED from v19's counted
// vmcnt which regressed) + even-qt dead-half skip:
//  * for segments with EVEN qt, the last 128-key tile's upper 64 keys are
//    fully masked (k >= (qt+1)*64 > all q-rows). v16 computed 16 exp2 and a
//    full 20-MFMA epilogue PV on that all-zero half. v20 writes 0 directly
//    (no exp2) and runs the epilogue PV with only 2 of 4 c-chunks — exact,
//    since ap[2..3] are identically zero.
// Rest = v16: operand-swapped S^T=K*Q^T; sigma-permuted VT; KVBLK=128;
// 17 tiles per pair {31-p,p}; PV(kt-1) overlaps softmax; V tri-buf + K dbuf
// (80 KB, 2 blocks/CU); ones-MFMA rowsum; cvt_pk P-packing; no-max softmax
// (Q pre-scaled by log2e/8); XCD map g=bid&7 -> bh [4g,4g+4).
// ---------------------------------------------------------------------------
__global__ __launch_bounds__(256, 2) void attn_kernel(
    const bf16_t* __restrict__ Q, const bf16_t* __restrict__ K,
    const bf16_t* __restrict__ VT, bf16_t* __restrict__ O) {
  __shared__ __align__(16) bf16_t Ks[2][128 * 64];  // K dbuf, 32 KB
  __shared__ __align__(16) bf16_t Vt[3][64 * 128];  // V tri-buf, 48 KB

  const int tid = threadIdx.x;
  const int w = tid >> 6, l = tid & 63;
  const int lq = l & 15, qd = l >> 4;
  const int bid = blockIdx.x;
  const int g = bid & 7, t = bid >> 3;  // 64 blocks per XCD-group
  const int bh = g * 4 + (t & 3);       // 4 bh per XCD-group: L2-resident K/VT
  const int p = t >> 2;                 // pair index: q-tiles {31-p, p}
  const int b = bh >> 4, h = bh & 15;
  const size_t rowbase = (size_t)b * S;
  const bf16_t* Kg = K + rowbase * E + h * 64;
  const bf16_t* Vg = VT + (size_t)bh * 64 * S;

  bf16x8 ones;
#pragma unroll
  for (int jj = 0; jj < 8; ++jj) ones[jj] = (bf16_t)1.0f;

  // prefetch 128-key tile 0 into K slot 0 / V slot 0
  stage_tile<128, 256>(Kg, E, Ks[0], tid);
  stage_v128(Vg, S, Vt[0], tid);
  int cb = 0, vcur = 0;

#pragma unroll 1
  for (int seg = 0; seg < 2; ++seg) {
    const int qt = seg ? p : 31 - p;    // heavy q-tile first
    const int T = (qt + 2) >> 1;        // 128-key tiles this segment
    const int qr = qt * 64 + w * 16;    // wave rows [qr, qr+16)
    const int qg = qr + lq;             // this lane's query row
    const bool evenqt = ((qt & 1) == 0);  // last tile's upper half dead

    bf16x8 aq[2];
#pragma unroll
    for (int ks = 0; ks < 2; ++ks)
      aq[ks] = *(const bf16x8*)(Q + (rowbase + qr + lq) * E + h * 64 +
                                ks * 32 + qd * 8);

    f32x4 oacc[4];
#pragma unroll
    for (int nt = 0; nt < 4; ++nt) oacc[nt] = (f32x4){0.f, 0.f, 0.f, 0.f};
    f32x4 osum = (f32x4){0.f, 0.f, 0.f, 0.f};
    bf16x8 ap_prev[4];                   // P frags of tile kt-1 (128 keys)
    int vprev = vcur;

    // PV of the previous tile: nc c-chunks (nc*4 oacc-MFMA + nc ones-MFMA)
    auto do_pv = [&](const bf16_t* Vp, int nc) {
#pragma unroll
      for (int c = 0; c < 4; ++c) {
        if (c >= nc) break;
        bf16x8 bv[4];
#pragma unroll
        for (int nt = 0; nt < 4; ++nt)
          bv[nt] = read_v128(Vp, nt * 16 + lq, c * 4 + qd);
#pragma unroll
        for (int nt = 0; nt < 4; ++nt)
          oacc[nt] = MFMA16(ap_prev[c], bv[nt], oacc[nt]);
        osum = MFMA16(ap_prev[c], ones, osum);
      }
    };

    for (int kt = 0; kt < T; ++kt) {
      __syncthreads();  // drains DMA into K[cb]/V[vcur]; all waves' reads of
                        // the slots being rewritten completed last iteration
      const int vnext = (vcur + 1 == 3) ? 0 : vcur + 1;
      if (kt < T - 1) {
        const int kn = (kt + 1) * 128;
        stage_tile<128, 256>(Kg + (size_t)kn * E, E, Ks[cb ^ 1], tid);
        stage_v128(Vg + kn, S, Vt[vnext], tid);
      } else if (seg == 0) {      // last A-iter: prefetch segment B's tile 0
        stage_tile<128, 256>(Kg, E, Ks[cb ^ 1], tid);
        stage_v128(Vg, S, Vt[vnext], tid);
      }
      const bf16_t* Kc = Ks[cb];
      const int k0 = kt * 128;
      const bool needmask = (kt == T - 1);

      // ---- S^T = K * Q^T : 16 MFMA; lane holds q=lq, keys nt*16+qd*4+r ----
      f32x4 sacc[8];
#pragma unroll
      for (int nt = 0; nt < 8; ++nt) sacc[nt] = (f32x4){0.f, 0.f, 0.f, 0.f};
      __builtin_amdgcn_s_setprio(1);
#pragma unroll
      for (int ks = 0; ks < 2; ++ks) {
        bf16x8 bk[8];
#pragma unroll
        for (int nt = 0; nt < 8; ++nt)
          bk[nt] = read_frag(Kc, nt * 16 + lq, ks * 4 + qd);
#pragma unroll
        for (int nt = 0; nt < 8; ++nt)
          sacc[nt] = MFMA16(bk[nt], aq[ks], sacc[nt]);
      }
      // ---- PV of tile kt-1 (independent; overlaps softmax below) ----
      if (kt > 0) do_pv(Vt[vprev], 4);
      __builtin_amdgcn_s_setprio(0);

      // ---- softmax: exp2 in f32 (mask on f32), pack via v_cvt_pk_bf16_f32 ----
      float pvf[8][4];
      if (needmask) {
#pragma unroll
        for (int nt = 0; nt < 8; ++nt)
#pragma unroll
          for (int r = 0; r < 4; ++r) {
            if (nt >= 4 && evenqt) {  // dead upper half: no exp2 needed
              pvf[nt][r] = 0.f;
            } else {
              float pv = __builtin_amdgcn_exp2f(sacc[nt][r]);
              const int kg = k0 + nt * 16 + qd * 4 + r;
              pvf[nt][r] = (kg > qg) ? 0.f : pv;
            }
          }
      } else {
#pragma unroll
        for (int nt = 0; nt < 8; ++nt)
#pragma unroll
          for (int r = 0; r < 4; ++r)
            pvf[nt][r] = __builtin_amdgcn_exp2f(sacc[nt][r]);
      }
#pragma unroll
      for (int c = 0; c < 4; ++c) {
        union { unsigned u[4]; bf16x8 v; } pk;
        pk.u[0] = cvtpk(pvf[2 * c][0], pvf[2 * c][1]);
        pk.u[1] = cvtpk(pvf[2 * c][2], pvf[2 * c][3]);
        pk.u[2] = cvtpk(pvf[2 * c + 1][0], pvf[2 * c + 1][1]);
        pk.u[3] = cvtpk(pvf[2 * c + 1][2], pvf[2 * c + 1][3]);
        ap_prev[c] = pk.v;
      }
      vprev = vcur;
      vcur = vnext;
      cb ^= 1;
    }
    // epilogue: PV of the segment's last (masked) tile; for even qt its
    // upper 2 c-chunks are identically zero -> skip (exact).
    do_pv(Vt[vprev], evenqt ? 2 : 4);

    // normalize + store: osum[r] = rowsum for q-row qd*4+r = C-layout rows
    float rinv[4];
#pragma unroll
    for (int r = 0; r < 4; ++r) rinv[r] = 1.0f / osum[r];
#pragma unroll
    for (int nt = 0; nt < 4; ++nt)
#pragma unroll
      for (int r = 0; r < 4; ++r) {
        const int qgw = qr + qd * 4 + r;
        O[(rowbase + qgw) * E + h * 64 + nt * 16 + lq] =
            (bf16_t)(oacc[nt][r] * rinv[r]);
      }
  }
}

// ---------------------------------------------------------------------------
// launch
// ---------------------------------------------------------------------------
extern "C" void kernel_launch(void* const* d_in, const int* in_sizes, int n_in,
                              void* d_out, int out_size, void* d_ws, size_t ws_size,
                              hipStream_t stream) {
  const float* x  = (const float*)d_in[0];
  const float* Wq = (const float*)d_in[1];
  const float* bq = (const float*)d_in[2];
  const float* Wk = (const float*)d_in[3];
  const float* bk = (const float*)d_in[4];
  const float* Wv = (const float*)d_in[5];
  const float* bv = (const float*)d_in[6];
  const float* Wo = (const float*)d_in[7];
  const float* bo = (const float*)d_in[8];
  float* out = (float*)d_out;

  unsigned char* ws = (unsigned char*)d_ws;
  constexpr size_t MB = 1ull << 20;
  bf16_t* xb  = (bf16_t*)(ws + 0 * MB);   // 8 MB; reused as Ob after qkv
  bf16_t* wqb = (bf16_t*)(ws + 8 * MB);   // wq/wk/wv contiguous [3072][1024]
  bf16_t* wkb = (bf16_t*)(ws + 10 * MB);
  bf16_t* wvb = (bf16_t*)(ws + 12 * MB);
  bf16_t* wob = (bf16_t*)(ws + 14 * MB);
  bf16_t* Qb  = (bf16_t*)(ws + 16 * MB);  // Q/K contiguous [2][4096][1024]
  bf16_t* VT  = (bf16_t*)(ws + 40 * MB);  // [32 bh][64 d][2048 s, sigma-perm per 64]
  bf16_t* Ob  = xb;                       // xb dead after qkv

  cvt_all_kernel<<<4096, 256, 0, stream>>>(
      x, Wq, Wk, Wv, Wo, xb, wqb, wkb, wvb, wob);

  qkv8_kernel<<<256, 512, 0, stream>>>(xb, wqb, bq, bk, bv, Qb, VT);

  attn_kernel<<<512, 256, 0, stream>>>(Qb, Qb + (size_t)M * E, VT, Ob);

  oproj_gemm_kernel<<<512, 256, 0, stream>>>(Ob, wob, bo, out);
}